// Round 7
// baseline (215.800 us; speedup 1.0000x reference)
//
#include <hip/hip_runtime.h>
#include <hip/hip_bf16.h>
#include <math.h>

#define BB 2
#define SS 2048
#define EE 1024
#define HH 16
#define DD 64
#define MM (BB*SS)          // 4096 rows
#define ND (HH*DD)          // 1024 concat width

typedef unsigned short u16;
typedef __attribute__((ext_vector_type(8))) short short8;   // 8 bf16 = one MFMA operand
typedef __attribute__((ext_vector_type(4))) float f32x4;    // MFMA accumulator

static __device__ __forceinline__ u16 f2b(float f) {
    __hip_bfloat16 h = __float2bfloat16(f);   // RNE
    return *reinterpret_cast<u16*>(&h);
}

// async global->LDS, 16B per lane; LDS dest is wave-uniform base + lane*16
#define GLDS16(gp, lp) __builtin_amdgcn_global_load_lds( \
    (const __attribute__((address_space(1))) void*)(gp), \
    (__attribute__((address_space(3))) void*)(lp), 16, 0, 0)

// attn LDS swizzles (u16 units), validated: SQ_LDS_BANK_CONFLICT == 0 on HW
#define KIDX(r,d) ((((r)*64 + (d))) ^ (((r)&7)<<3))
#define VIDX(d,k) ((((d)*64 + (k))) ^ (((d)&7)<<3))
#define PIDX(q,k) ((((q)*64 + (k))) ^ (((q)&7)<<3))

// ---------------------------------------------------------------------------
// Kernel A: cast x fp32 -> bf16 row-major.
// ---------------------------------------------------------------------------
__global__ __launch_bounds__(256) void cast_x_kernel(
    const float* __restrict__ x, u16* __restrict__ xb)
{
    const size_t i = ((size_t)blockIdx.x * 256 + threadIdx.x) * 8;
    float4 a = *(const float4*)(x + i);
    float4 b = *(const float4*)(x + i + 4);
    unsigned p[4];
    p[0] = f2b(a.x) | ((unsigned)f2b(a.y) << 16);
    p[1] = f2b(a.z) | ((unsigned)f2b(a.w) << 16);
    p[2] = f2b(b.x) | ((unsigned)f2b(b.y) << 16);
    p[3] = f2b(b.z) | ((unsigned)f2b(b.w) << 16);
    *(uint4*)(xb + i) = *(uint4*)p;
}

// ---------------------------------------------------------------------------
// Kernel B: weight transpose-cast -> Wt[4][1024 n][1024 k] bf16.
// ---------------------------------------------------------------------------
__global__ __launch_bounds__(256) void wtrans_kernel(
    const float* __restrict__ Wq, const float* __restrict__ Wk,
    const float* __restrict__ Wv, const float* __restrict__ Wo,
    u16* __restrict__ Wt)
{
    const int et = blockIdx.x, y = blockIdx.y, z = blockIdx.z;
    const float* src = (z == 0) ? Wq : (z == 1) ? Wk : (z == 2) ? Wv : Wo;
    const size_t rstride = (z < 3) ? 64 : 1024;
    const float* base = (z < 3) ? (src + (size_t)y * 65536) : (src + y * 64);
    u16* out = Wt + ((size_t)z * 1024 + y * 64) * 1024;

    __shared__ float Ts[64][65];
    const int tid = threadIdx.x;
    {
        const int r = tid >> 2, cq = (tid & 3) * 16;
        const float* ip = base + (size_t)(et * 64 + r) * rstride + cq;
        #pragma unroll
        for (int i = 0; i < 4; ++i)
            *(float4*)&Ts[r][cq + i * 4] = *(const float4*)(ip + i * 4);
    }
    __syncthreads();
    {
        const int c = tid >> 2, eq = (tid & 3) * 16;
        unsigned p[8];
        #pragma unroll
        for (int i = 0; i < 8; ++i)
            p[i] = f2b(Ts[eq + 2 * i][c]) | ((unsigned)f2b(Ts[eq + 2 * i + 1][c]) << 16);
        u16* opp = out + (size_t)c * 1024 + et * 64 + eq;
        *(uint4*)opp       = *(uint4*)&p[0];
        *(uint4*)(opp + 8) = *(uint4*)&p[4];
    }
}

// ---------------------------------------------------------------------------
// Kernel C: fused QKV projection, bf16 MFMA, 2-phase double-buffered staging
// (T3 minimum 2-phase: issue STAGE(t+1) -> ds_read/MFMA(t) -> one barrier).
// Grid (32, 24): by>>3 selects Q/K/V, (by&7)*128 is the n-tile.
// ---------------------------------------------------------------------------
__global__ __launch_bounds__(256) void qkv_gemm_kernel(
    const u16* __restrict__ xb, const u16* __restrict__ Wt,
    const float* __restrict__ bq, const float* __restrict__ bk,
    const float* __restrict__ bv,
    u16* __restrict__ Qb, u16* __restrict__ Kb, u16* __restrict__ Vt)
{
    const int mat = blockIdx.y >> 3;
    const u16* Bt = Wt + (size_t)mat * 1024 * 1024;
    const float* bias = (mat == 0) ? bq : (mat == 1) ? bk : bv;

    const int m0 = blockIdx.x * 128;
    const int n0 = (blockIdx.y & 7) * 128;

    __shared__ u16 As[2][128 * 32];   // [buf][row][k] linear, 2 x 8 KB
    __shared__ u16 Bs[2][128 * 32];

    const int tid = threadIdx.x;
    const int w = tid >> 6, l = tid & 63;
    const int wr = (w >> 1) * 64, wc = (w & 1) * 64;
    const int lg = l >> 4, lm = l & 15;

    f32x4 acc[4][4];
    const f32x4 zero4 = {0.f, 0.f, 0.f, 0.f};
    #pragma unroll
    for (int i = 0; i < 4; ++i)
        #pragma unroll
        for (int j = 0; j < 4; ++j) acc[i][j] = zero4;

    const int lrow = l >> 2;           // 0..15
    const int lk   = (l & 3) * 8;
    const u16* Ag = xb + (size_t)(m0 + w * 32 + lrow) * EE + lk;
    const u16* Bg = Bt + (size_t)(n0 + w * 32 + lrow) * EE + lk;

    #define QKV_STAGE(buf, koff) do { \
        GLDS16(Ag + (koff),            &As[buf][(w * 32) * 32]); \
        GLDS16(Ag + (koff) + 16 * EE,  &As[buf][(w * 32 + 16) * 32]); \
        GLDS16(Bg + (koff),            &Bs[buf][(w * 32) * 32]); \
        GLDS16(Bg + (koff) + 16 * EE,  &Bs[buf][(w * 32 + 16) * 32]); \
    } while (0)

    #define QKV_COMPUTE(buf) do { \
        short8 af[4], bf[4]; \
        _Pragma("unroll") \
        for (int ft = 0; ft < 4; ++ft) \
            af[ft] = *(const short8*)&As[buf][(wr + ft * 16 + lm) * 32 + lg * 8]; \
        _Pragma("unroll") \
        for (int fn = 0; fn < 4; ++fn) \
            bf[fn] = *(const short8*)&Bs[buf][(wc + fn * 16 + lm) * 32 + lg * 8]; \
        _Pragma("unroll") \
        for (int ft = 0; ft < 4; ++ft) \
            _Pragma("unroll") \
            for (int fn = 0; fn < 4; ++fn) \
                acc[ft][fn] = __builtin_amdgcn_mfma_f32_16x16x32_bf16( \
                    af[ft], bf[fn], acc[ft][fn], 0, 0, 0); \
    } while (0)

    // prologue: stage tile 0 into buf 0 (implicit vmcnt(0) at barrier)
    QKV_STAGE(0, 0);
    __syncthreads();

    // steady state: stage t+1 into buf^1 BEFORE computing t; one barrier/step
    for (int k0 = 0; k0 < EE - 32; k0 += 32) {
        const int cur = (k0 >> 5) & 1;
        QKV_STAGE(cur ^ 1, k0 + 32);
        QKV_COMPUTE(cur);
        __syncthreads();
    }
    QKV_COMPUTE(1);   // tile 31 lives in buf 1

    if (mat == 2) {
        #pragma unroll
        for (int ft = 0; ft < 4; ++ft) {
            const int mrow = m0 + wr + ft * 16 + lg * 4;
            const int bidx = mrow >> 11, s0 = mrow & 2047;
            #pragma unroll
            for (int fn = 0; fn < 4; ++fn) {
                const int n = n0 + wc + fn * 16 + lm;
                const float bb = bias[n];
                const f32x4 a = acc[ft][fn];
                uint2 pp;
                pp.x = f2b(a[0] + bb) | ((unsigned)f2b(a[1] + bb) << 16);
                pp.y = f2b(a[2] + bb) | ((unsigned)f2b(a[3] + bb) << 16);
                *(uint2*)(Vt + ((size_t)(bidx * 1024 + n)) * SS + s0) = pp;
            }
        }
    } else {
        u16* out = (mat == 0) ? Qb : Kb;
        const float alpha = (mat == 0) ? 0.18033688011112042f : 1.0f; // 0.125*log2e
        #pragma unroll
        for (int ft = 0; ft < 4; ++ft)
            #pragma unroll
            for (int c = 0; c < 4; ++c) {
                const size_t row = m0 + wr + ft * 16 + lg * 4 + c;
                #pragma unroll
                for (int fn = 0; fn < 4; ++fn) {
                    const int n = n0 + wc + fn * 16 + lm;
                    out[row * ND + n] = f2b((acc[ft][fn][c] + bias[n]) * alpha);
                }
            }
    }
    #undef QKV_STAGE
    #undef QKV_COMPUTE
}

// ---------------------------------------------------------------------------
// Kernel D: causal flash attention (validated round 6, unchanged).
// ---------------------------------------------------------------------------
__global__ __launch_bounds__(256, 4) void attn_kernel(
    const u16* __restrict__ Qb, const u16* __restrict__ Kb,
    const u16* __restrict__ Vt, u16* __restrict__ Ob)
{
    const int bid = blockIdx.x;
    const int qt = 31 - (bid >> 5);          // heavy q-tiles first
    const int bh = bid & 31;
    const int b = bh >> 4, h = bh & 15;

    const int tid = threadIdx.x;
    const int w  = tid >> 6;
    const int l  = tid & 63;
    const int lg = l >> 4;
    const int lm = l & 15;

    __shared__ u16 Ks [2][64 * 64];
    __shared__ u16 Vts[2][64 * 64];
    __shared__ u16 Ps [4][16 * 64];

    const int qbase = qt * 64 + w * 16;

    short8 qf0, qf1;
    {
        const u16* qp = Qb + ((size_t)(b * SS + qbase + lm)) * ND + h * DD + lg * 8;
        qf0 = *(const short8*)qp;
        qf1 = *(const short8*)(qp + 32);
    }

    short8 onesb;
    #pragma unroll
    for (int j = 0; j < 8; ++j) onesb[j] = (short)0x3F80;

    f32x4 o[4];
    const f32x4 zero4 = {0.f, 0.f, 0.f, 0.f};
    #pragma unroll
    for (int dt = 0; dt < 4; ++dt) o[dt] = zero4;
    f32x4 lacc = zero4;

    const int nt = qt + 1;

    const int sr  = tid >> 3;
    const int sc8 = (tid & 7) * 8;
    const u16* KbBase = Kb + ((size_t)(b * SS)) * ND + h * DD + sc8;
    const u16* VtBase = Vt + ((size_t)bh * DD) * SS + sc8;

    short8 kA, kB, vA, vB;
    {
        kA = *(const short8*)(KbBase + (size_t)(sr)      * ND);
        kB = *(const short8*)(KbBase + (size_t)(sr + 32) * ND);
        vA = *(const short8*)(VtBase + (size_t)(sr)      * SS);
        vB = *(const short8*)(VtBase + (size_t)(sr + 32) * SS);
        *(short8*)&Ks [0][KIDX(sr,      sc8)] = kA;
        *(short8*)&Ks [0][KIDX(sr + 32, sc8)] = kB;
        *(short8*)&Vts[0][VIDX(sr,      sc8)] = vA;
        *(short8*)&Vts[0][VIDX(sr + 32, sc8)] = vB;
    }
    __syncthreads();

    for (int t = 0; t < nt; ++t) {
        const int cur = t & 1;
        const bool pf = (t + 1 < nt);
        if (pf) {   // T14: issue next tile's loads; compute hides latency
            const int kv1 = (t + 1) * 64;
            kA = *(const short8*)(KbBase + (size_t)(kv1 + sr)      * ND);
            kB = *(const short8*)(KbBase + (size_t)(kv1 + sr + 32) * ND);
            vA = *(const short8*)(VtBase + (size_t)(sr)      * SS + kv1);
            vB = *(const short8*)(VtBase + (size_t)(sr + 32) * SS + kv1);
        }

        const u16* Kc = &Ks[cur][0];
        const u16* Vc = &Vts[cur][0];
        f32x4 sc[4];
        #pragma unroll
        for (int ts = 0; ts < 4; ++ts) {
            short8 kb0 = *(const short8*)&Kc[KIDX(16 * ts + lm, lg * 8)];
            short8 kb1 = *(const short8*)&Kc[KIDX(16 * ts + lm, 32 + lg * 8)];
            sc[ts] = __builtin_amdgcn_mfma_f32_16x16x32_bf16(qf0, kb0, zero4, 0, 0, 0);
            sc[ts] = __builtin_amdgcn_mfma_f32_16x16x32_bf16(qf1, kb1, sc[ts], 0, 0, 0);
        }

        if (t == qt) {   // causal mask, diagonal tile only
            const int kv0 = t * 64;
            #pragma unroll
            for (int ts = 0; ts < 4; ++ts)
                #pragma unroll
                for (int r4 = 0; r4 < 4; ++r4)
                    if (kv0 + 16 * ts + lm > qbase + lg * 4 + r4)
                        sc[ts][r4] = -3.0e38f;   // exp2 -> 0
        }

        u16* Pw = &Ps[w][0];
        #pragma unroll
        for (int ts = 0; ts < 4; ++ts)
            #pragma unroll
            for (int c = 0; c < 4; ++c)
                Pw[PIDX(lg * 4 + c, 16 * ts + lm)] = f2b(exp2f(sc[ts][c]));
        asm volatile("s_waitcnt lgkmcnt(0)" ::: "memory");  // own-wave visibility

        short8 pa0 = *(const short8*)&Pw[PIDX(lm, lg * 8)];
        short8 pa1 = *(const short8*)&Pw[PIDX(lm, 32 + lg * 8)];
        lacc = __builtin_amdgcn_mfma_f32_16x16x32_bf16(pa0, onesb, lacc, 0, 0, 0);
        lacc = __builtin_amdgcn_mfma_f32_16x16x32_bf16(pa1, onesb, lacc, 0, 0, 0);
        #pragma unroll
        for (int dt = 0; dt < 4; ++dt) {
            short8 vb0 = *(const short8*)&Vc[VIDX(16 * dt + lm, lg * 8)];
            short8 vb1 = *(const short8*)&Vc[VIDX(16 * dt + lm, 32 + lg * 8)];
            o[dt] = __builtin_amdgcn_mfma_f32_16x16x32_bf16(pa0, vb0, o[dt], 0, 0, 0);
            o[dt] = __builtin_amdgcn_mfma_f32_16x16x32_bf16(pa1, vb1, o[dt], 0, 0, 0);
        }

        if (pf) {
            const int nb = cur ^ 1;
            *(short8*)&Ks [nb][KIDX(sr,      sc8)] = kA;
            *(short8*)&Ks [nb][KIDX(sr + 32, sc8)] = kB;
            *(short8*)&Vts[nb][VIDX(sr,      sc8)] = vA;
            *(short8*)&Vts[nb][VIDX(sr + 32, sc8)] = vB;
        }
        __syncthreads();
    }

    u16* op = Ob + ((size_t)(b * SS + qbase)) * ND + h * DD;
    #pragma unroll
    for (int c = 0; c < 4; ++c) {
        const float inv = 1.f / lacc[c];
        #pragma unroll
        for (int dt = 0; dt < 4; ++dt)
            op[(size_t)(lg * 4 + c) * ND + 16 * dt + lm] = f2b(o[dt][c] * inv);
    }
}

// ---------------------------------------------------------------------------
// Kernel E: output projection, bf16 MFMA, 2-phase double-buffered staging.
// ---------------------------------------------------------------------------
__global__ __launch_bounds__(256) void out_gemm_kernel(
    const u16* __restrict__ Ob, const u16* __restrict__ WoT,
    const float* __restrict__ bo, float* __restrict__ out)
{
    const int m0 = blockIdx.x * 128;
    const int n0 = blockIdx.y * 128;

    __shared__ u16 As[2][128 * 32];
    __shared__ u16 Bs[2][128 * 32];

    const int tid = threadIdx.x;
    const int w = tid >> 6, l = tid & 63;
    const int wr = (w >> 1) * 64, wc = (w & 1) * 64;
    const int lg = l >> 4, lm = l & 15;

    f32x4 acc[4][4];
    const f32x4 zero4 = {0.f, 0.f, 0.f, 0.f};
    #pragma unroll
    for (int i = 0; i < 4; ++i)
        #pragma unroll
        for (int j = 0; j < 4; ++j) acc[i][j] = zero4;

    const int lrow = l >> 2;
    const int lk   = (l & 3) * 8;
    const u16* Ag = Ob  + (size_t)(m0 + w * 32 + lrow) * EE + lk;
    const u16* Bg = WoT + (size_t)(n0 + w * 32 + lrow) * EE + lk;

    #define OUT_STAGE(buf, koff) do { \
        GLDS16(Ag + (koff),            &As[buf][(w * 32) * 32]); \
        GLDS16(Ag + (koff) + 16 * EE,  &As[buf][(w * 32 + 16) * 32]); \
        GLDS16(Bg + (koff),            &Bs[buf][(w * 32) * 32]); \
        GLDS16(Bg + (koff) + 16 * EE,  &Bs[buf][(w * 32 + 16) * 32]); \
    } while (0)

    #define OUT_COMPUTE(buf) do { \
        short8 af[4], bf[4]; \
        _Pragma("unroll") \
        for (int ft = 0; ft < 4; ++ft) \
            af[ft] = *(const short8*)&As[buf][(wr + ft * 16 + lm) * 32 + lg * 8]; \
        _Pragma("unroll") \
        for (int fn = 0; fn < 4; ++fn) \
            bf[fn] = *(const short8*)&Bs[buf][(wc + fn * 16 + lm) * 32 + lg * 8]; \
        _Pragma("unroll") \
        for (int ft = 0; ft < 4; ++ft) \
            _Pragma("unroll") \
            for (int fn = 0; fn < 4; ++fn) \
                acc[ft][fn] = __builtin_amdgcn_mfma_f32_16x16x32_bf16( \
                    af[ft], bf[fn], acc[ft][fn], 0, 0, 0); \
    } while (0)

    OUT_STAGE(0, 0);
    __syncthreads();
    for (int k0 = 0; k0 < EE - 32; k0 += 32) {
        const int cur = (k0 >> 5) & 1;
        OUT_STAGE(cur ^ 1, k0 + 32);
        OUT_COMPUTE(cur);
        __syncthreads();
    }
    OUT_COMPUTE(1);

    #pragma unroll
    for (int ft = 0; ft < 4; ++ft)
        #pragma unroll
        for (int c = 0; c < 4; ++c) {
            const size_t row = m0 + wr + ft * 16 + lg * 4 + c;
            #pragma unroll
            for (int fn = 0; fn < 4; ++fn) {
                const int n = n0 + wc + fn * 16 + lm;
                out[row * EE + n] = acc[ft][fn][c] + bo[n];
            }
        }
    #undef OUT_STAGE
    #undef OUT_COMPUTE
}

// ---------------------------------------------------------------------------
extern "C" void kernel_launch(void* const* d_in, const int* in_sizes, int n_in,
                              void* d_out, int out_size, void* d_ws, size_t ws_size,
                              hipStream_t stream)
{
    const float* x  = (const float*)d_in[0];
    const float* Wq = (const float*)d_in[1];
    const float* bq = (const float*)d_in[2];
    const float* Wk = (const float*)d_in[3];
    const float* bk = (const float*)d_in[4];
    const float* Wv = (const float*)d_in[5];
    const float* bv = (const float*)d_in[6];
    const float* Wo = (const float*)d_in[7];
    const float* bo = (const float*)d_in[8];
    float* out = (float*)d_out;

    // ws (u16 units): xb | Wt[4] | Qb | Kb | Vt | Ob  = 48 MB total
    u16* xb = (u16*)d_ws;
    u16* Wt = xb + (size_t)MM * EE;
    u16* Qb = Wt + (size_t)4 * 1024 * 1024;
    u16* Kb = Qb + (size_t)MM * ND;
    u16* Vt = Kb + (size_t)MM * ND;            // [b*1024 + h*64 + d][s]
    u16* Ob = Vt + (size_t)MM * ND;

    cast_x_kernel<<<dim3((MM * EE) / (256 * 8)), 256, 0, stream>>>(x, xb);
    wtrans_kernel<<<dim3(16, 16, 4), 256, 0, stream>>>(Wq, Wk, Wv, Wo, Wt);
    qkv_gemm_kernel<<<dim3(MM / 128, 24), 256, 0, stream>>>(
        xb, Wt, bq, bk, bv, Qb, Kb, Vt);
    attn_kernel<<<dim3(1024), 256, 0, stream>>>(Qb, Kb, Vt, Ob);
    out_gemm_kernel<<<dim3(MM / 128, EE / 128), 256, 0, stream>>>(
        Ob, Wt + (size_t)3 * 1024 * 1024, bo, out);
}

// Round 9
// 193.905 us; speedup vs baseline: 1.1129x; 1.1129x over previous
//
#include <hip/hip_runtime.h>
#include <hip/hip_bf16.h>
#include <math.h>

#define BB 2
#define SS 2048
#define EE 1024
#define HH 16
#define DD 64
#define MM (BB*SS)          // 4096 rows
#define ND (HH*DD)          // 1024 concat width

typedef unsigned short u16;
typedef __attribute__((ext_vector_type(8))) short short8;   // 8 bf16 = one MFMA operand
typedef __attribute__((ext_vector_type(4))) float f32x4;    // MFMA accumulator

static __device__ __forceinline__ u16 f2b(float f) {
    __hip_bfloat16 h = __float2bfloat16(f);   // RNE
    return *reinterpret_cast<u16*>(&h);
}

// async global->LDS, 16B per lane; LDS dest is wave-uniform base + lane*16
#define GLDS16(gp, lp) __builtin_amdgcn_global_load_lds( \
    (const __attribute__((address_space(1))) void*)(gp), \
    (__attribute__((address_space(3))) void*)(lp), 16, 0, 0)

// attn LDS swizzles (u16 units), validated: SQ_LDS_BANK_CONFLICT == 0 on HW
#define KIDX(r,d) ((((r)*64 + (d))) ^ (((r)&7)<<3))
#define VIDX(d,k) ((((d)*64 + (k))) ^ (((d)&7)<<3))
#define PIDX(q,k) ((((q)*64 + (k))) ^ (((q)&7)<<3))

// ---------------------------------------------------------------------------
// Kernel A: cast x fp32 -> bf16 row-major.
// ---------------------------------------------------------------------------
__global__ __launch_bounds__(256) void cast_x_kernel(
    const float* __restrict__ x, u16* __restrict__ xb)
{
    const size_t i = ((size_t)blockIdx.x * 256 + threadIdx.x) * 8;
    float4 a = *(const float4*)(x + i);
    float4 b = *(const float4*)(x + i + 4);
    unsigned p[4];
    p[0] = f2b(a.x) | ((unsigned)f2b(a.y) << 16);
    p[1] = f2b(a.z) | ((unsigned)f2b(a.w) << 16);
    p[2] = f2b(b.x) | ((unsigned)f2b(b.y) << 16);
    p[3] = f2b(b.z) | ((unsigned)f2b(b.w) << 16);
    *(uint4*)(xb + i) = *(uint4*)p;
}

// ---------------------------------------------------------------------------
// Kernel B: weight transpose-cast -> Wt[4][1024 n][1024 k] bf16.
// ---------------------------------------------------------------------------
__global__ __launch_bounds__(256) void wtrans_kernel(
    const float* __restrict__ Wq, const float* __restrict__ Wk,
    const float* __restrict__ Wv, const float* __restrict__ Wo,
    u16* __restrict__ Wt)
{
    const int et = blockIdx.x, y = blockIdx.y, z = blockIdx.z;
    const float* src = (z == 0) ? Wq : (z == 1) ? Wk : (z == 2) ? Wv : Wo;
    const size_t rstride = (z < 3) ? 64 : 1024;
    const float* base = (z < 3) ? (src + (size_t)y * 65536) : (src + y * 64);
    u16* out = Wt + ((size_t)z * 1024 + y * 64) * 1024;

    __shared__ float Ts[64][65];
    const int tid = threadIdx.x;
    {
        const int r = tid >> 2, cq = (tid & 3) * 16;
        const float* ip = base + (size_t)(et * 64 + r) * rstride + cq;
        #pragma unroll
        for (int i = 0; i < 4; ++i)
            *(float4*)&Ts[r][cq + i * 4] = *(const float4*)(ip + i * 4);
    }
    __syncthreads();
    {
        const int c = tid >> 2, eq = (tid & 3) * 16;
        unsigned p[8];
        #pragma unroll
        for (int i = 0; i < 8; ++i)
            p[i] = f2b(Ts[eq + 2 * i][c]) | ((unsigned)f2b(Ts[eq + 2 * i + 1][c]) << 16);
        u16* opp = out + (size_t)c * 1024 + et * 64 + eq;
        *(uint4*)opp       = *(uint4*)&p[0];
        *(uint4*)(opp + 8) = *(uint4*)&p[4];
    }
}

// ---------------------------------------------------------------------------
// Kernel C: fused QKV projection, bf16 MFMA.  m97-style single-buffer
// 2-barrier schedule, BK=64: each vmcnt drain covers 32 MFMA/wave.
// LDS chunk-swizzle (both-sides rule #21): global source pre-swizzled with
// chunk ^ (row&7), GLDS16 dest linear, frag reads at (kc ^ (row&7)) ->
// uniform 8 lanes per bank-slot on ds_read_b128.
// Grid (32, 24): by>>3 selects Q/K/V, (by&7)*128 is the n-tile.
// ---------------------------------------------------------------------------
__global__ __launch_bounds__(256) void qkv_gemm_kernel(
    const u16* __restrict__ xb, const u16* __restrict__ Wt,
    const float* __restrict__ bq, const float* __restrict__ bk,
    const float* __restrict__ bv,
    u16* __restrict__ Qb, u16* __restrict__ Kb, u16* __restrict__ Vt)
{
    const int mat = blockIdx.y >> 3;
    const u16* Bt = Wt + (size_t)mat * 1024 * 1024;
    const float* bias = (mat == 0) ? bq : (mat == 1) ? bk : bv;

    const int m0 = blockIdx.x * 128;
    const int n0 = (blockIdx.y & 7) * 128;

    __shared__ u16 As[128 * 64];   // [row][64k] linear (source pre-swizzled), 16 KB
    __shared__ u16 Bs[128 * 64];

    const int tid = threadIdx.x;
    const int w = tid >> 6, l = tid & 63;
    const int wr = (w >> 1) * 64, wc = (w & 1) * 64;
    const int lg = l >> 4, lm = l & 15;
    const int lm7 = lm & 7;

    f32x4 acc[4][4];
    const f32x4 zero4 = {0.f, 0.f, 0.f, 0.f};
    #pragma unroll
    for (int i = 0; i < 4; ++i)
        #pragma unroll
        for (int j = 0; j < 4; ++j) acc[i][j] = zero4;

    // staging: lane l of wave w, call j covers LDS row w*32 + j*8 + (l>>3);
    // global col chunk is pre-swizzled: (l&7) ^ (l>>3)  (= chunk ^ (row&7))
    const int srow = l >> 3;                    // 0..7
    const int scc  = ((l & 7) ^ srow) * 8;      // swizzled global col (elems)
    const u16* Ag = xb + (size_t)(m0 + w * 32 + srow) * EE + scc;
    const u16* Bg = Bt + (size_t)(n0 + w * 32 + srow) * EE + scc;

    for (int k0 = 0; k0 < EE; k0 += 64) {
        #pragma unroll
        for (int j = 0; j < 4; ++j) {
            GLDS16(Ag + k0 + j * 8 * EE, &As[(w * 32 + j * 8) * 64]);
            GLDS16(Bg + k0 + j * 8 * EE, &Bs[(w * 32 + j * 8) * 64]);
        }
        __syncthreads();
        #pragma unroll
        for (int kk = 0; kk < 2; ++kk) {
            const int kc = kk * 4 + lg;             // k-chunk 0..7
            short8 af[4], bf[4];
            #pragma unroll
            for (int ft = 0; ft < 4; ++ft)
                af[ft] = *(const short8*)&As[(wr + ft * 16 + lm) * 64 + ((kc ^ lm7) * 8)];
            #pragma unroll
            for (int fn = 0; fn < 4; ++fn)
                bf[fn] = *(const short8*)&Bs[(wc + fn * 16 + lm) * 64 + ((kc ^ lm7) * 8)];
            #pragma unroll
            for (int ft = 0; ft < 4; ++ft)
                #pragma unroll
                for (int fn = 0; fn < 4; ++fn)
                    acc[ft][fn] = __builtin_amdgcn_mfma_f32_16x16x32_bf16(
                        af[ft], bf[fn], acc[ft][fn], 0, 0, 0);
        }
        __syncthreads();
    }

    if (mat == 2) {
        #pragma unroll
        for (int ft = 0; ft < 4; ++ft) {
            const int mrow = m0 + wr + ft * 16 + lg * 4;
            const int bidx = mrow >> 11, s0 = mrow & 2047;
            #pragma unroll
            for (int fn = 0; fn < 4; ++fn) {
                const int n = n0 + wc + fn * 16 + lm;
                const float bb = bias[n];
                const f32x4 a = acc[ft][fn];
                uint2 pp;
                pp.x = f2b(a[0] + bb) | ((unsigned)f2b(a[1] + bb) << 16);
                pp.y = f2b(a[2] + bb) | ((unsigned)f2b(a[3] + bb) << 16);
                *(uint2*)(Vt + ((size_t)(bidx * 1024 + n)) * SS + s0) = pp;
            }
        }
    } else {
        u16* out = (mat == 0) ? Qb : Kb;
        const float alpha = (mat == 0) ? 0.18033688011112042f : 1.0f; // 0.125*log2e
        #pragma unroll
        for (int ft = 0; ft < 4; ++ft)
            #pragma unroll
            for (int c = 0; c < 4; ++c) {
                const size_t row = m0 + wr + ft * 16 + lg * 4 + c;
                #pragma unroll
                for (int fn = 0; fn < 4; ++fn) {
                    const int n = n0 + wc + fn * 16 + lm;
                    out[row * ND + n] = f2b((acc[ft][fn][c] + bias[n]) * alpha);
                }
            }
    }
}

// ---------------------------------------------------------------------------
// Kernel D: causal flash attention (validated rounds 5-6, unchanged).
// ---------------------------------------------------------------------------
__global__ __launch_bounds__(256, 4) void attn_kernel(
    const u16* __restrict__ Qb, const u16* __restrict__ Kb,
    const u16* __restrict__ Vt, u16* __restrict__ Ob)
{
    const int bid = blockIdx.x;
    const int qt = 31 - (bid >> 5);          // heavy q-tiles first
    const int bh = bid & 31;
    const int b = bh >> 4, h = bh & 15;

    const int tid = threadIdx.x;
    const int w  = tid >> 6;
    const int l  = tid & 63;
    const int lg = l >> 4;
    const int lm = l & 15;

    __shared__ u16 Ks [2][64 * 64];
    __shared__ u16 Vts[2][64 * 64];
    __shared__ u16 Ps [4][16 * 64];

    const int qbase = qt * 64 + w * 16;

    short8 qf0, qf1;
    {
        const u16* qp = Qb + ((size_t)(b * SS + qbase + lm)) * ND + h * DD + lg * 8;
        qf0 = *(const short8*)qp;
        qf1 = *(const short8*)(qp + 32);
    }

    short8 onesb;
    #pragma unroll
    for (int j = 0; j < 8; ++j) onesb[j] = (short)0x3F80;

    f32x4 o[4];
    const f32x4 zero4 = {0.f, 0.f, 0.f, 0.f};
    #pragma unroll
    for (int dt = 0; dt < 4; ++dt) o[dt] = zero4;
    f32x4 lacc = zero4;

    const int nt = qt + 1;

    const int sr  = tid >> 3;
    const int sc8 = (tid & 7) * 8;
    const u16* KbBase = Kb + ((size_t)(b * SS)) * ND + h * DD + sc8;
    const u16* VtBase = Vt + ((size_t)bh * DD) * SS + sc8;

    short8 kA, kB, vA, vB;
    {
        kA = *(const short8*)(KbBase + (size_t)(sr)      * ND);
        kB = *(const short8*)(KbBase + (size_t)(sr + 32) * ND);
        vA = *(const short8*)(VtBase + (size_t)(sr)      * SS);
        vB = *(const short8*)(VtBase + (size_t)(sr + 32) * SS);
        *(short8*)&Ks [0][KIDX(sr,      sc8)] = kA;
        *(short8*)&Ks [0][KIDX(sr + 32, sc8)] = kB;
        *(short8*)&Vts[0][VIDX(sr,      sc8)] = vA;
        *(short8*)&Vts[0][VIDX(sr + 32, sc8)] = vB;
    }
    __syncthreads();

    for (int t = 0; t < nt; ++t) {
        const int cur = t & 1;
        const bool pf = (t + 1 < nt);
        if (pf) {   // T14: issue next tile's loads; compute hides latency
            const int kv1 = (t + 1) * 64;
            kA = *(const short8*)(KbBase + (size_t)(kv1 + sr)      * ND);
            kB = *(const short8*)(KbBase + (size_t)(kv1 + sr + 32) * ND);
            vA = *(const short8*)(VtBase + (size_t)(sr)      * SS + kv1);
            vB = *(const short8*)(VtBase + (size_t)(sr + 32) * SS + kv1);
        }

        const u16* Kc = &Ks[cur][0];
        const u16* Vc = &Vts[cur][0];
        f32x4 sc[4];
        #pragma unroll
        for (int ts = 0; ts < 4; ++ts) {
            short8 kb0 = *(const short8*)&Kc[KIDX(16 * ts + lm, lg * 8)];
            short8 kb1 = *(const short8*)&Kc[KIDX(16 * ts + lm, 32 + lg * 8)];
            sc[ts] = __builtin_amdgcn_mfma_f32_16x16x32_bf16(qf0, kb0, zero4, 0, 0, 0);
            sc[ts] = __builtin_amdgcn_mfma_f32_16x16x32_bf16(qf1, kb1, sc[ts], 0, 0, 0);
        }

        if (t == qt) {   // causal mask, diagonal tile only
            const int kv0 = t * 64;
            #pragma unroll
            for (int ts = 0; ts < 4; ++ts)
                #pragma unroll
                for (int r4 = 0; r4 < 4; ++r4)
                    if (kv0 + 16 * ts + lm > qbase + lg * 4 + r4)
                        sc[ts][r4] = -3.0e38f;   // exp2 -> 0
        }

        u16* Pw = &Ps[w][0];
        #pragma unroll
        for (int ts = 0; ts < 4; ++ts)
            #pragma unroll
            for (int c = 0; c < 4; ++c)
                Pw[PIDX(lg * 4 + c, 16 * ts + lm)] = f2b(exp2f(sc[ts][c]));
        asm volatile("s_waitcnt lgkmcnt(0)" ::: "memory");  // own-wave visibility

        short8 pa0 = *(const short8*)&Pw[PIDX(lm, lg * 8)];
        short8 pa1 = *(const short8*)&Pw[PIDX(lm, 32 + lg * 8)];
        lacc = __builtin_amdgcn_mfma_f32_16x16x32_bf16(pa0, onesb, lacc, 0, 0, 0);
        lacc = __builtin_amdgcn_mfma_f32_16x16x32_bf16(pa1, onesb, lacc, 0, 0, 0);
        #pragma unroll
        for (int dt = 0; dt < 4; ++dt) {
            short8 vb0 = *(const short8*)&Vc[VIDX(16 * dt + lm, lg * 8)];
            short8 vb1 = *(const short8*)&Vc[VIDX(16 * dt + lm, 32 + lg * 8)];
            o[dt] = __builtin_amdgcn_mfma_f32_16x16x32_bf16(pa0, vb0, o[dt], 0, 0, 0);
            o[dt] = __builtin_amdgcn_mfma_f32_16x16x32_bf16(pa1, vb1, o[dt], 0, 0, 0);
        }

        if (pf) {
            const int nb = cur ^ 1;
            *(short8*)&Ks [nb][KIDX(sr,      sc8)] = kA;
            *(short8*)&Ks [nb][KIDX(sr + 32, sc8)] = kB;
            *(short8*)&Vts[nb][VIDX(sr,      sc8)] = vA;
            *(short8*)&Vts[nb][VIDX(sr + 32, sc8)] = vB;
        }
        __syncthreads();
    }

    u16* op = Ob + ((size_t)(b * SS + qbase)) * ND + h * DD;
    #pragma unroll
    for (int c = 0; c < 4; ++c) {
        const float inv = 1.f / lacc[c];
        #pragma unroll
        for (int dt = 0; dt < 4; ++dt)
            op[(size_t)(lg * 4 + c) * ND + 16 * dt + lm] = f2b(o[dt][c] * inv);
    }
}

// ---------------------------------------------------------------------------
// Kernel E: output projection, bf16 MFMA, BK=64 single-buffer (same as C).
// ---------------------------------------------------------------------------
__global__ __launch_bounds__(256) void out_gemm_kernel(
    const u16* __restrict__ Ob, const u16* __restrict__ WoT,
    const float* __restrict__ bo, float* __restrict__ out)
{
    const int m0 = blockIdx.x * 128;
    const int n0 = blockIdx.y * 128;

    __shared__ u16 As[128 * 64];
    __shared__ u16 Bs[128 * 64];

    const int tid = threadIdx.x;
    const int w = tid >> 6, l = tid & 63;
    const int wr = (w >> 1) * 64, wc = (w & 1) * 64;
    const int lg = l >> 4, lm = l & 15;
    const int lm7 = lm & 7;

    f32x4 acc[4][4];
    const f32x4 zero4 = {0.f, 0.f, 0.f, 0.f};
    #pragma unroll
    for (int i = 0; i < 4; ++i)
        #pragma unroll
        for (int j = 0; j < 4; ++j) acc[i][j] = zero4;

    const int srow = l >> 3;
    const int scc  = ((l & 7) ^ srow) * 8;
    const u16* Ag = Ob  + (size_t)(m0 + w * 32 + srow) * EE + scc;
    const u16* Bg = WoT + (size_t)(n0 + w * 32 + srow) * EE + scc;

    for (int k0 = 0; k0 < EE; k0 += 64) {
        #pragma unroll
        for (int j = 0; j < 4; ++j) {
            GLDS16(Ag + k0 + j * 8 * EE, &As[(w * 32 + j * 8) * 64]);
            GLDS16(Bg + k0 + j * 8 * EE, &Bs[(w * 32 + j * 8) * 64]);
        }
        __syncthreads();
        #pragma unroll
        for (int kk = 0; kk < 2; ++kk) {
            const int kc = kk * 4 + lg;
            short8 af[4], bf[4];
            #pragma unroll
            for (int ft = 0; ft < 4; ++ft)
                af[ft] = *(const short8*)&As[(wr + ft * 16 + lm) * 64 + ((kc ^ lm7) * 8)];
            #pragma unroll
            for (int fn = 0; fn < 4; ++fn)
                bf[fn] = *(const short8*)&Bs[(wc + fn * 16 + lm) * 64 + ((kc ^ lm7) * 8)];
            #pragma unroll
            for (int ft = 0; ft < 4; ++ft)
                #pragma unroll
                for (int fn = 0; fn < 4; ++fn)
                    acc[ft][fn] = __builtin_amdgcn_mfma_f32_16x16x32_bf16(
                        af[ft], bf[fn], acc[ft][fn], 0, 0, 0);
        }
        __syncthreads();
    }

    #pragma unroll
    for (int ft = 0; ft < 4; ++ft)
        #pragma unroll
        for (int c = 0; c < 4; ++c) {
            const size_t row = m0 + wr + ft * 16 + lg * 4 + c;
            #pragma unroll
            for (int fn = 0; fn < 4; ++fn) {
                const int n = n0 + wc + fn * 16 + lm;
                out[row * EE + n] = acc[ft][fn][c] + bo[n];
            }
        }
}

// ---------------------------------------------------------------------------
extern "C" void kernel_launch(void* const* d_in, const int* in_sizes, int n_in,
                              void* d_out, int out_size, void* d_ws, size_t ws_size,
                              hipStream_t stream)
{
    const float* x  = (const float*)d_in[0];
    const float* Wq = (const float*)d_in[1];
    const float* bq = (const float*)d_in[2];
    const float* Wk = (const float*)d_in[3];
    const float* bk = (const float*)d_in[4];
    const float* Wv = (const float*)d_in[5];
    const float* bv = (const float*)d_in[6];
    const float* Wo = (const float*)d_in[7];
    const float* bo = (const float*)d_in[8];
    float* out = (float*)d_out;

    // ws (u16 units): xb | Wt[4] | Qb | Kb | Vt | Ob  = 48 MB total
    u16* xb = (u16*)d_ws;
    u16* Wt = xb + (size_t)MM * EE;
    u16* Qb = Wt + (size_t)4 * 1024 * 1024;
    u16* Kb = Qb + (size_t)MM * ND;
    u16* Vt = Kb + (size_t)MM * ND;            // [b*1024 + h*64 + d][s]
    u16* Ob = Vt + (size_t)MM * ND;

    cast_x_kernel<<<dim3((MM * EE) / (256 * 8)), 256, 0, stream>>>(x, xb);
    wtrans_kernel<<<dim3(16, 16, 4), 256, 0, stream>>>(Wq, Wk, Wv, Wo, Wt);
    qkv_gemm_kernel<<<dim3(MM / 128, 24), 256, 0, stream>>>(
        xb, Wt, bq, bk, bv, Qb, Kb, Vt);
    attn_kernel<<<dim3(1024), 256, 0, stream>>>(Qb, Kb, Vt, Ob);
    out_gemm_kernel<<<dim3(MM / 128, EE / 128), 256, 0, stream>>>(
        Ob, Wt + (size_t)3 * 1024 * 1024, bo, out);
}